// Round 1
// baseline (617.639 us; speedup 1.0000x reference)
//
#include <hip/hip_runtime.h>
#include <hip/hip_bf16.h>
#include <math.h>

#define B_ 32
#define O_ 2
#define N_ 4096
#define D_ 128
#define M_ (O_*N_)        // 8192
#define NT 64             // rows per block in logits kernel
#define NTILES (N_/NT)    // 64
#define MC 512            // m per block in weighted-sum kernel

// ---------------------------------------------------------------------------
// K1: cvec[b][i][e] = bu[i][e] + sum_d x[b,i,last[b,i],d] * Wv[i,e,d]
// ---------------------------------------------------------------------------
__global__ __launch_bounds__(128) void k_cvec(const float* __restrict__ x,
        const float* __restrict__ Wv, const float* __restrict__ bu,
        const int* __restrict__ last, float* __restrict__ cvec)
{
    int bi = blockIdx.x;            // b*O_ + i
    int b = bi >> 1, i = bi & 1;
    int e = threadIdx.x;
    __shared__ float xl[D_];
    int ln = last[bi];
    const float* xrow = x + (((size_t)b*O_ + i)*N_ + ln)*D_;
    xl[e] = xrow[e];
    __syncthreads();
    const float* wv = Wv + ((size_t)i*D_ + e)*D_;
    float acc = bu[i*D_ + e];
    #pragma unroll 8
    for (int d = 0; d < D_; ++d) acc += xl[d]*wv[d];
    cvec[bi*D_ + e] = acc;
}

// ---------------------------------------------------------------------------
// K2: logits[b][i][o*N+n] = sum_e sigmoid( (x[b,o,n,:] . Wu[i,e,:]) + cvec[b,i,e] ) * We[i,e]
// Block: 256 threads = 4 waves. thread t: row r = t&63 (n within tile),
// e-quarter q = t>>6. x rows live in registers (float4 x8 per d-chunk),
// Wu[i][e][dchunk] staged in LDS and read as wave-uniform broadcasts.
// ---------------------------------------------------------------------------
__global__ __launch_bounds__(256) void k_logits(const float* __restrict__ x,
        const float* __restrict__ Wu, const float* __restrict__ cvec,
        const float* __restrict__ We, float* __restrict__ logits)
{
    int blk   = blockIdx.x;
    int ntile = blk % NTILES;
    int o     = (blk / NTILES) % O_;
    int b     = blk / (NTILES*O_);
    int t = threadIdx.x;
    int r = t & 63;
    int q = t >> 6;

    __shared__ float xs[NT][132];        // +4 pad: row stride 132 -> banks spread
    __shared__ float wus[D_][32];        // one 32-wide d-chunk of Wu[i], all 128 e
    __shared__ float partial[4][NT];

    int n0 = ntile*NT;
    const float* xbase = x + (((size_t)b*O_ + o)*N_ + n0)*D_;

    // stage x tile: 64 rows x 128 floats, coalesced float4
    #pragma unroll
    for (int it = 0; it < 8; ++it) {
        int idx = it*256 + t;            // 0..2047 float4 slots
        int row = idx >> 5;              // 32 float4 per row
        int col = idx & 31;
        float4 v = *(const float4*)(xbase + row*D_ + col*4);
        *(float4*)&xs[row][col*4] = v;
    }
    // (visibility of xs covered by the first __syncthreads below)

    for (int i = 0; i < O_; ++i) {
        float acc[32];
        #pragma unroll
        for (int el = 0; el < 32; ++el) acc[el] = 0.f;

        for (int dc = 0; dc < 4; ++dc) {
            // stage Wu[i][:, dc*32 .. dc*32+31]
            const float* wub = Wu + ((size_t)i*D_)*D_ + dc*32;
            #pragma unroll
            for (int it = 0; it < 4; ++it) {
                int idx = it*256 + t;    // 0..1023 float4 slots
                int e = idx >> 3;        // 8 float4 per e-row
                int c = idx & 7;
                float4 v = *(const float4*)(wub + e*D_ + c*4);
                *(float4*)&wus[e][c*4] = v;
            }
            __syncthreads();

            // x chunk into registers
            float4 xr[8];
            #pragma unroll
            for (int j = 0; j < 8; ++j)
                xr[j] = *(const float4*)&xs[r][dc*32 + j*4];

            #pragma unroll
            for (int el = 0; el < 32; ++el) {
                int e = q*32 + el;
                const float* wrow = &wus[e][0];   // wave-uniform -> broadcast reads
                float s = 0.f;
                #pragma unroll
                for (int j = 0; j < 8; ++j) {
                    float4 w = *(const float4*)(wrow + j*4);
                    s += xr[j].x*w.x + xr[j].y*w.y + xr[j].z*w.z + xr[j].w*w.w;
                }
                acc[el] += s;
            }
            __syncthreads();
        }

        // epilogue: sigmoid gate + dot with We, reduce across quarters
        int bi = b*O_ + i;
        const float* cv = cvec + bi*D_ + q*32;
        const float* we = We + i*D_ + q*32;
        float p = 0.f;
        #pragma unroll
        for (int el = 0; el < 32; ++el) {
            float z = acc[el] + cv[el];
            float s = 1.f/(1.f + __expf(-z));
            p += s*we[el];
        }
        partial[q][r] = p;
        __syncthreads();
        if (q == 0) {
            float lg = partial[0][r] + partial[1][r] + partial[2][r] + partial[3][r];
            logits[(size_t)bi*M_ + o*N_ + n0 + r] = lg;
        }
        __syncthreads();
    }
}

// ---------------------------------------------------------------------------
// K3a: per (b,i): max and 1/sum(exp) over 8192 logits
// ---------------------------------------------------------------------------
__global__ __launch_bounds__(256) void k_stats(const float* __restrict__ logits,
        float* __restrict__ stats)
{
    int bi = blockIdx.x, t = threadIdx.x;
    const float* lg = logits + (size_t)bi*M_;
    __shared__ float red[4];
    __shared__ float red2[4];

    float mx = -1e30f;
    for (int m = t; m < M_; m += 256) mx = fmaxf(mx, lg[m]);
    #pragma unroll
    for (int off = 32; off >= 1; off >>= 1) mx = fmaxf(mx, __shfl_xor(mx, off));
    if ((t & 63) == 0) red[t >> 6] = mx;
    __syncthreads();
    mx = fmaxf(fmaxf(red[0], red[1]), fmaxf(red[2], red[3]));

    float sm = 0.f;
    for (int m = t; m < M_; m += 256) sm += __expf(lg[m] - mx);
    #pragma unroll
    for (int off = 32; off >= 1; off >>= 1) sm += __shfl_xor(sm, off);
    if ((t & 63) == 0) red2[t >> 6] = sm;
    __syncthreads();
    if (t == 0) {
        sm = red2[0] + red2[1] + red2[2] + red2[3];
        stats[bi*2]     = mx;
        stats[bi*2 + 1] = 1.f/sm;
    }
}

// ---------------------------------------------------------------------------
// K3b: partial weighted sums: part[bi][chunk][d] = sum_{m in chunk} alpha_m * x[b,m,d]
// ---------------------------------------------------------------------------
__global__ __launch_bounds__(128) void k_wsum(const float* __restrict__ logits,
        const float* __restrict__ stats, const float* __restrict__ x,
        float* __restrict__ part)
{
    int blk = blockIdx.x;          // bi*16 + chunk
    int chunk = blk & 15;
    int bi = blk >> 4;
    int b = bi >> 1;
    int t = threadIdx.x;           // d
    float mx  = stats[bi*2];
    float inv = stats[bi*2 + 1];
    const float* lg = logits + (size_t)bi*M_;
    float acc = 0.f;
    int m0 = chunk*MC;
    #pragma unroll 8
    for (int mm = 0; mm < MC; ++mm) {
        int m = m0 + mm;
        float w = __expf(lg[m] - mx)*inv;        // lg[m] wave-uniform -> broadcast
        const float* xr = x + ((size_t)b*M_ + m)*D_;  // x[b][o][n] flat: (b*8192+m)*128
        acc += w * xr[t];
    }
    part[(size_t)blk*D_ + t] = acc;
}

// ---------------------------------------------------------------------------
// K3c: deterministic reduction of the 16 chunks per (b,i)
// ---------------------------------------------------------------------------
__global__ __launch_bounds__(128) void k_red(const float* __restrict__ part,
        float* __restrict__ out)
{
    int bi = blockIdx.x, t = threadIdx.x;
    float s = 0.f;
    #pragma unroll
    for (int c = 0; c < 16; ++c) s += part[(size_t)(bi*16 + c)*D_ + t];
    out[bi*D_ + t] = s;
}

extern "C" void kernel_launch(void* const* d_in, const int* in_sizes, int n_in,
                              void* d_out, int out_size, void* d_ws, size_t ws_size,
                              hipStream_t stream) {
    const float* x    = (const float*)d_in[0];
    const float* Wu   = (const float*)d_in[1];
    const float* bu   = (const float*)d_in[2];
    const float* Wv   = (const float*)d_in[3];
    const float* We   = (const float*)d_in[4];
    const int*   last = (const int*)d_in[5];
    float* out = (float*)d_out;

    // workspace layout (floats)
    float* ws      = (float*)d_ws;
    float* logits  = ws;                                  // B*O*M = 524288
    float* cvec    = logits + (size_t)B_*O_*M_;           // B*O*D = 8192
    float* stats   = cvec + B_*O_*D_;                     // B*O*2 = 128
    float* part    = stats + B_*O_*2;                     // 64*16*128 = 131072

    k_cvec  <<<B_*O_, 128, 0, stream>>>(x, Wv, bu, last, cvec);
    k_logits<<<B_*O_*NTILES, 256, 0, stream>>>(x, Wu, cvec, We, logits);
    k_stats <<<B_*O_, 256, 0, stream>>>(logits, stats);
    k_wsum  <<<B_*O_*(M_/MC), 128, 0, stream>>>(logits, stats, x, part);
    k_red   <<<B_*O_, 128, 0, stream>>>(part, out);
}

// Round 3
// 100.416 us; speedup vs baseline: 6.1508x; 6.1508x over previous
//
#include <hip/hip_runtime.h>
#include <hip/hip_bf16.h>
#include <math.h>

#define B_ 32
#define O_ 2
#define N_ 4096
#define D_ 128
#define M_ (O_*N_)        // 8192
#define MC 512

typedef __bf16 bf16x8 __attribute__((ext_vector_type(8)));
typedef float  f32x4  __attribute__((ext_vector_type(4)));

// RTN-even fp32 -> bf16
static __device__ __forceinline__ unsigned short f2bf(float f) {
    unsigned int u = __float_as_uint(f);
    u += 0x7fffu + ((u >> 16) & 1u);
    return (unsigned short)(u >> 16);
}

// ---------------------------------------------------------------------------
// K0: Wu fp32 -> bf16 (once)
// ---------------------------------------------------------------------------
__global__ __launch_bounds__(256) void k_prep(const float* __restrict__ Wu,
        unsigned short* __restrict__ wub) {
    int idx = blockIdx.x*256 + threadIdx.x;
    wub[idx] = f2bf(Wu[idx]);
}

// ---------------------------------------------------------------------------
// K1: cvec[b][i][e] = bu[i][e] + sum_d x[b,i,last[b,i],d] * Wv[i,e,d]
// ---------------------------------------------------------------------------
__global__ __launch_bounds__(128) void k_cvec(const float* __restrict__ x,
        const float* __restrict__ Wv, const float* __restrict__ bu,
        const int* __restrict__ last, float* __restrict__ cvec)
{
    int bi = blockIdx.x;
    int b = bi >> 1, i = bi & 1;
    int e = threadIdx.x;
    __shared__ float xl[D_];
    int ln = last[bi];
    const float* xrow = x + (((size_t)b*O_ + i)*N_ + ln)*D_;
    xl[e] = xrow[e];
    __syncthreads();
    const float* wv = Wv + ((size_t)i*D_ + e)*D_;
    float acc = bu[i*D_ + e];
    #pragma unroll 8
    for (int d = 0; d < D_; ++d) acc += xl[d]*wv[d];
    cvec[bi*D_ + e] = acc;
}

// ---------------------------------------------------------------------------
// K2: MFMA logits. Block = 256 thr = 4 waves; 128 rows x 128 e per block.
// wave w: row-half wr=w>>1 (64 rows, M_rep=4), e-half wc=w&1 (64 e, N_rep=4).
// LDS layout (both xs and wus): row-major [row][128 bf16], with k within each
// 32-k group stored permuted as pos = 8*q + 4*h + j for k = 16h + 4q + j, and
// byte offset XOR-swizzled by ((row&15)<<4). Then an MFMA fragment is one
// contiguous 16B read at byte (ks*64 + (lane>>4)*16) ^ swizzle(row).
// ---------------------------------------------------------------------------
__global__ __launch_bounds__(256, 2) void k_logits_mfma(
        const float* __restrict__ x, const unsigned short* __restrict__ wub,
        const float* __restrict__ cvec, const float* __restrict__ We,
        float* __restrict__ logits)
{
    __shared__ uint4 ldsbuf[4096];                 // 64 KiB
    unsigned char* lds = (unsigned char*)ldsbuf;
    unsigned char* xsb = lds;                      // 32 KiB: x tile
    unsigned char* wsb = lds + 32768;              // 32 KiB: Wu[i]
    float* red = (float*)lds;                      // aliases xs (safe after A-frag loads)

    int blk  = blockIdx.x;
    int tile = blk & 31;
    int o    = (blk >> 5) & 1;
    int b    = blk >> 6;
    int n0   = tile * 128;

    int t = threadIdx.x;
    int l = t & 63;
    int w = t >> 6;
    int wr = w >> 1, wc = w & 1;
    int l15 = l & 15, lq = l >> 4;

    const float* xbase = x + (((size_t)b*O_ + o)*N_ + n0)*D_;

    // ---- stage x tile: fp32 -> bf16, k-permute + swizzle ----
    #pragma unroll
    for (int it = 0; it < 16; ++it) {
        int idx = it*256 + t;          // 4096 float4 chunks
        int row = idx >> 5;
        int c   = idx & 31;            // float4 chunk within row (k' = 4c..4c+3)
        float4 v = *(const float4*)(xbase + row*D_ + c*4);
        ushort4 h;
        h.x = f2bf(v.x); h.y = f2bf(v.y); h.z = f2bf(v.z); h.w = f2bf(v.w);
        int ks = c >> 3, cc = c & 7;
        int off = (ks*64 + (cc&3)*16 + (cc>>2)*8) ^ ((row & 15) << 4);
        *(ushort4*)(xsb + row*256 + off) = h;
    }
    __syncthreads();

    // ---- A fragments into registers (reused for both i) ----
    bf16x8 Af[4][4];
    #pragma unroll
    for (int ks = 0; ks < 4; ++ks) {
        #pragma unroll
        for (int m = 0; m < 4; ++m) {
            int row = wr*64 + m*16 + l15;
            int off = (ks*64 + lq*16) ^ ((row & 15) << 4);
            uint4 u = *(const uint4*)(xsb + row*256 + off);
            Af[ks][m] = __builtin_bit_cast(bf16x8, u);
        }
    }
    __syncthreads();   // all xs reads done before red aliasing

    f32x4 zero = {0.f, 0.f, 0.f, 0.f};

    for (int i = 0; i < O_; ++i) {
        // ---- stage Wu[i] (bf16), k-permute + swizzle: 128 rows x 32 chunks ----
        const unsigned short* wsrc = wub + i*D_*D_;
        #pragma unroll
        for (int it = 0; it < 16; ++it) {
            int idx = it*256 + t;      // 4096 8-byte chunks
            int e = idx >> 5;          // 32 chunks of 4 bf16 per e-row
            int c = idx & 31;
            int ks = c >> 3, cc = c & 7;
            int off = (ks*64 + (cc&3)*16 + (cc>>2)*8) ^ ((e & 15) << 4);
            *(ushort4*)(wsb + e*256 + off) = *(const ushort4*)(wsrc + e*D_ + c*4);
        }
        __syncthreads();

        f32x4 acc[4][4];
        #pragma unroll
        for (int m = 0; m < 4; ++m)
            #pragma unroll
            for (int n = 0; n < 4; ++n)
                acc[m][n] = zero;

        #pragma unroll
        for (int ks = 0; ks < 4; ++ks) {
            bf16x8 Bf[4];
            #pragma unroll
            for (int n = 0; n < 4; ++n) {
                int e = wc*64 + n*16 + l15;
                int off = (ks*64 + lq*16) ^ ((e & 15) << 4);
                uint4 u = *(const uint4*)(wsb + e*256 + off);
                Bf[n] = __builtin_bit_cast(bf16x8, u);
            }
            #pragma unroll
            for (int m = 0; m < 4; ++m)
                #pragma unroll
                for (int n = 0; n < 4; ++n)
                    acc[m][n] = __builtin_amdgcn_mfma_f32_16x16x32_bf16(
                        Af[ks][m], Bf[n], acc[m][n], 0, 0, 0);
        }
        __syncthreads();   // wus reads done (next stage overwrites it)

        // ---- epilogue: sigmoid gate, dot We, reduce over e ----
        int bi = b*O_ + i;
        float cv[4], wev[4];
        #pragma unroll
        for (int n = 0; n < 4; ++n) {
            int e = wc*64 + n*16 + l15;
            cv[n]  = cvec[bi*D_ + e];
            wev[n] = We[i*D_ + e];
        }
        #pragma unroll
        for (int m = 0; m < 4; ++m) {
            float pv[4] = {0.f, 0.f, 0.f, 0.f};
            #pragma unroll
            for (int n = 0; n < 4; ++n) {
                #pragma unroll
                for (int r = 0; r < 4; ++r) {
                    float z = acc[m][n][r] + cv[n];
                    float s = __builtin_amdgcn_rcpf(1.f + __expf(-z));
                    pv[r] += s * wev[n];
                }
            }
            #pragma unroll
            for (int off = 1; off < 16; off <<= 1) {
                #pragma unroll
                for (int r = 0; r < 4; ++r)
                    pv[r] += __shfl_xor(pv[r], off);
            }
            if (l15 == 0) {
                int rb = wr*64 + m*16 + lq*4;
                #pragma unroll
                for (int r = 0; r < 4; ++r)
                    red[wc*128 + rb + r] = pv[r];
            }
        }
        __syncthreads();
        if (t < 128)
            logits[(size_t)bi*M_ + o*N_ + n0 + t] = red[t] + red[128 + t];
        __syncthreads();
    }
}

// ---------------------------------------------------------------------------
// K3a: per (b,i): max and 1/sum(exp) over 8192 logits
// ---------------------------------------------------------------------------
__global__ __launch_bounds__(256) void k_stats(const float* __restrict__ logits,
        float* __restrict__ stats)
{
    int bi = blockIdx.x, t = threadIdx.x;
    const float* lg = logits + (size_t)bi*M_;
    __shared__ float red[4];
    __shared__ float red2[4];

    float mx = -1e30f;
    for (int m = t; m < M_; m += 256) mx = fmaxf(mx, lg[m]);
    #pragma unroll
    for (int off = 32; off >= 1; off >>= 1) mx = fmaxf(mx, __shfl_xor(mx, off));
    if ((t & 63) == 0) red[t >> 6] = mx;
    __syncthreads();
    mx = fmaxf(fmaxf(red[0], red[1]), fmaxf(red[2], red[3]));

    float sm = 0.f;
    for (int m = t; m < M_; m += 256) sm += __expf(lg[m] - mx);
    #pragma unroll
    for (int off = 32; off >= 1; off >>= 1) sm += __shfl_xor(sm, off);
    if ((t & 63) == 0) red2[t >> 6] = sm;
    __syncthreads();
    if (t == 0) {
        sm = red2[0] + red2[1] + red2[2] + red2[3];
        stats[bi*2]     = mx;
        stats[bi*2 + 1] = 1.f/sm;
    }
}

// ---------------------------------------------------------------------------
// K3b: partial weighted sums
// ---------------------------------------------------------------------------
__global__ __launch_bounds__(128) void k_wsum(const float* __restrict__ logits,
        const float* __restrict__ stats, const float* __restrict__ x,
        float* __restrict__ part)
{
    int blk = blockIdx.x;          // bi*16 + chunk
    int chunk = blk & 15;
    int bi = blk >> 4;
    int b = bi >> 1;
    int t = threadIdx.x;           // d
    float mx  = stats[bi*2];
    float inv = stats[bi*2 + 1];
    const float* lg = logits + (size_t)bi*M_;
    float acc = 0.f;
    int m0 = chunk*MC;
    #pragma unroll 8
    for (int mm = 0; mm < MC; ++mm) {
        int m = m0 + mm;
        float wgt = __expf(lg[m] - mx)*inv;
        const float* xr = x + ((size_t)b*M_ + m)*D_;
        acc += wgt * xr[t];
    }
    part[(size_t)blk*D_ + t] = acc;
}

// ---------------------------------------------------------------------------
// K3c: deterministic reduction of the 16 chunks per (b,i)
// ---------------------------------------------------------------------------
__global__ __launch_bounds__(128) void k_red(const float* __restrict__ part,
        float* __restrict__ out)
{
    int bi = blockIdx.x, t = threadIdx.x;
    float s = 0.f;
    #pragma unroll
    for (int c = 0; c < 16; ++c) s += part[(size_t)(bi*16 + c)*D_ + t];
    out[bi*D_ + t] = s;
}

extern "C" void kernel_launch(void* const* d_in, const int* in_sizes, int n_in,
                              void* d_out, int out_size, void* d_ws, size_t ws_size,
                              hipStream_t stream) {
    const float* x    = (const float*)d_in[0];
    const float* Wu   = (const float*)d_in[1];
    const float* bu   = (const float*)d_in[2];
    const float* Wv   = (const float*)d_in[3];
    const float* We   = (const float*)d_in[4];
    const int*   last = (const int*)d_in[5];
    float* out = (float*)d_out;

    // workspace layout (floats)
    float* ws      = (float*)d_ws;
    float* logits  = ws;                                  // 524288
    float* cvec    = logits + (size_t)B_*O_*M_;           // 8192
    float* stats   = cvec + B_*O_*D_;                     // 128
    float* part    = stats + B_*O_*2;                     // 131072
    unsigned short* wub = (unsigned short*)(part + (size_t)B_*O_*16*D_); // 32768 bf16

    k_prep       <<<128, 256, 0, stream>>>(Wu, wub);
    k_cvec       <<<B_*O_, 128, 0, stream>>>(x, Wv, bu, last, cvec);
    k_logits_mfma<<<B_*O_*(N_/128), 256, 0, stream>>>(x, wub, cvec, We, logits);
    k_stats      <<<B_*O_, 256, 0, stream>>>(logits, stats);
    k_wsum       <<<B_*O_*(M_/MC), 128, 0, stream>>>(logits, stats, x, part);
    k_red        <<<B_*O_, 128, 0, stream>>>(part, out);
}